// Round 12
// baseline (81.411 us; speedup 1.0000x reference)
//
#include <hip/hip_runtime.h>
#include <math.h>

#define NN 32
#define CC 512
#define PP 1024   // H*W
#define KK 64
static constexpr float EPS = 1e-12f;

typedef __attribute__((ext_vector_type(8))) short bf16x8;
typedef __attribute__((ext_vector_type(4))) float f32x4;
typedef __attribute__((ext_vector_type(4))) unsigned int u32x4;
union FragU { u32x4 u; bf16x8 h; };

// pack two fp32 into one u32 of 2 bf16 (RNE)
__device__ __forceinline__ unsigned int bfpair(float lo, float hi) {
    unsigned int ul = __builtin_bit_cast(unsigned int, lo);
    unsigned int uh = __builtin_bit_cast(unsigned int, hi);
    ul = ul + 0x7FFFu + ((ul >> 16) & 1u);
    uh = uh + 0x7FFFu + ((uh >> 16) & 1u);
    return (ul >> 16) | (uh & 0xFFFF0000u);
}

// ---------------- w [K][C] fp32 -> wpk [K][C/2] u32 (bf16 pairs, k-major) ----------------
__global__ void k_wprep(const float* __restrict__ w, unsigned int* __restrict__ wpk) {
    int i = blockIdx.x * 256 + threadIdx.x;   // over K*C/2 = 16384
    wpk[i] = bfpair(w[2 * i], w[2 * i + 1]);
}

// ---------------- partial logits (MFMA) over a 256-c half + ssq partials ----------------
// grid: 512 blocks = n(32) x 128-px tile(8) x c-half(2). 512 threads = 8 waves.
// LDS ~70KB -> 2 blocks/CU (16 waves/CU, vs 8 for the old monolithic kernel).
__global__ void __launch_bounds__(512, 2) k_lgemm(
        const float* __restrict__ x, const unsigned int* __restrict__ wpk,
        float* __restrict__ lgpart, float* __restrict__ ssqpart) {
    int b = blockIdx.x;
    int h = b & 1;
    int pt = (b >> 1) & 7;
    int n = b >> 4;
    int p0 = pt << 7;
    int tid = threadIdx.x;
    int lane = tid & 63;
    int wv = __builtin_amdgcn_readfirstlane(tid >> 6);   // 0..7 = px tile
    int l15 = lane & 15, l4 = lane >> 4;
    int rp = tid >> 4;               // staging cpair row 0..31
    int px8 = (tid & 15) << 3;       // staging px octet

    __shared__ unsigned int smem_u[17792];   // 71168 B -> 2 blocks/CU
    unsigned int* XP = smem_u;               // 2 x [128][33] u32 (x bf16 c-pairs)
    unsigned int* WC = smem_u + 8448;        // [64][130] u32 (w half, bf16 c-pairs)
    float* RED = (float*)(smem_u + 16768);   // [8][128] ssq partials

    // ---- stage W half once ----
    {
        int k = tid >> 3;
        int c16 = (tid & 7) << 4;
        const unsigned int* wsrc = wpk + (k << 8) + (h << 7) + c16;
        unsigned int* wdst = WC + k * 130 + c16;
#pragma unroll
        for (int i = 0; i < 4; ++i)
            *(u32x4*)(wdst + (i << 2)) = *(const u32x4*)(wsrc + (i << 2));
    }

    const float* xb = x + ((size_t)n * CC + h * 256) * PP + p0;

    f32x4 c0v = {0.f, 0.f, 0.f, 0.f};
    f32x4 c1v = {0.f, 0.f, 0.f, 0.f};
    f32x4 c2v = {0.f, 0.f, 0.f, 0.f};
    f32x4 c3v = {0.f, 0.f, 0.f, 0.f};
    float ssq[8] = {};
    float4 a0, a1, b0, b1;

#define PFL(i) { const float* xa = xb + (size_t)((i) * 64 + 2 * rp) * PP + px8; \
        a0 = *(const float4*)xa; a1 = *(const float4*)(xa + 4); \
        b0 = *(const float4*)(xa + PP); b1 = *(const float4*)(xa + PP + 4); }

#define MSTEP(H) { \
        FragU bfr; \
        int ob = xo + ((H) << 4); \
        bfr.u[0] = xq[ob]; bfr.u[1] = xq[ob + 1]; \
        bfr.u[2] = xq[ob + 2]; bfr.u[3] = xq[ob + 3]; \
        int oa = l15 * 130 + (i << 5) + ((H) << 4) + (l4 << 2); \
        FragU af; \
        af.u = *(const u32x4*)&WC[oa]; \
        c0v = __builtin_amdgcn_mfma_f32_16x16x32_bf16(af.h, bfr.h, c0v, 0, 0, 0); \
        af.u = *(const u32x4*)&WC[oa + 2080]; \
        c1v = __builtin_amdgcn_mfma_f32_16x16x32_bf16(af.h, bfr.h, c1v, 0, 0, 0); \
        af.u = *(const u32x4*)&WC[oa + 4160]; \
        c2v = __builtin_amdgcn_mfma_f32_16x16x32_bf16(af.h, bfr.h, c2v, 0, 0, 0); \
        af.u = *(const u32x4*)&WC[oa + 6240]; \
        c3v = __builtin_amdgcn_mfma_f32_16x16x32_bf16(af.h, bfr.h, c3v, 0, 0, 0); \
    }

    PFL(0);
#pragma unroll 1
    for (int i = 0; i < 4; ++i) {
        __syncthreads();                      // buffer free (+W visible at i==0)
        int bo = (i & 1) * 4224;
        unsigned int* xp = XP + bo;
        float av[8] = {a0.x, a0.y, a0.z, a0.w, a1.x, a1.y, a1.z, a1.w};
        float bv[8] = {b0.x, b0.y, b0.z, b0.w, b1.x, b1.y, b1.z, b1.w};
#pragma unroll
        for (int j = 0; j < 8; ++j) {
            xp[(px8 + j) * 33 + rp] = bfpair(av[j], bv[j]);
            ssq[j] = fmaf(av[j], av[j], fmaf(bv[j], bv[j], ssq[j]));
        }
        if (i < 3) { PFL(i + 1); }
        __syncthreads();                      // staged chunk visible
        const unsigned int* xq = XP + bo;
        int xo = (wv * 16 + l15) * 33 + (l4 << 2);
        MSTEP(0);
        MSTEP(1);
    }
#undef PFL
#undef MSTEP

    // ---- ssq partials for this half ----
#pragma unroll
    for (int j = 0; j < 8; ++j) {
        ssq[j] += __shfl_xor(ssq[j], 16);
        ssq[j] += __shfl_xor(ssq[j], 32);
    }
    if (l4 == 0) {
#pragma unroll
        for (int j = 0; j < 8; ++j) RED[(wv << 7) + px8 + j] = ssq[j];
    }
    __syncthreads();
    if (tid < 128) {
        float s = 0.f;
#pragma unroll
        for (int w8 = 0; w8 < 8; ++w8) s += RED[(w8 << 7) + tid];
        ssqpart[((size_t)(h * NN + n) << 10) + p0 + tid] = s;
    }

    // ---- raw fp32 logit partials ----
    float* lp = lgpart + (((size_t)(h * NN + n) * KK) << 10) + p0 + (wv << 4) + l15;
#pragma unroll
    for (int r = 0; r < 4; ++r) {
        int kb = (l4 << 2) + r;
        lp[(size_t)kb << 10]        = c0v[r];
        lp[(size_t)(16 + kb) << 10] = c1v[r];
        lp[(size_t)(32 + kb) << 10] = c2v[r];
        lp[(size_t)(48 + kb) << 10] = c3v[r];
    }
}

// ---------------- combine halves + pixnorm + softmax -> sab (bf16 pairs), inv_n ----------------
// grid: 256 blocks = n(32) x 128-px tile(8). 256 threads (px = tid&127, k-half = tid>>7).
__global__ void __launch_bounds__(256) k_combine(
        const float* __restrict__ lgpart, const float* __restrict__ ssqpart,
        const float* __restrict__ bias, float* __restrict__ inv_n,
        unsigned int* __restrict__ sab) {
    int b = blockIdx.x;
    int n = b >> 3;
    int p0 = (b & 7) << 7;
    int tid = threadIdx.x;
    int px = tid & 127, kh = tid >> 7;

    __shared__ float LT[64 * 132];   // 33.8 KB
    __shared__ float IVS[128];
    __shared__ float MX[2][128];
    __shared__ float SM[2][128];

    const float* lp0 = lgpart + (((size_t)n * KK) << 10) + p0;
    const float* lp1 = lgpart + (((size_t)(NN + n) * KK) << 10) + p0;
    for (int e = tid; e < 8192; e += 256) {
        int k = e >> 7, q = e & 127;
        LT[k * 132 + q] = lp0[((size_t)k << 10) + q] + lp1[((size_t)k << 10) + q];
    }
    if (tid < 128) {
        float s = ssqpart[((size_t)n << 10) + p0 + tid]
                + ssqpart[((size_t)(NN + n) << 10) + p0 + tid];
        float iv = 1.0f / fmaxf(sqrtf(s), EPS);
        inv_n[(n << 10) + p0 + tid] = iv;
        IVS[tid] = iv;
    }
    __syncthreads();

    float iv = IVS[px];
    float l[32];
    float m = -1e30f;
#pragma unroll
    for (int j = 0; j < 32; ++j) {
        int k = (kh << 5) + j;
        l[j] = fmaf(LT[k * 132 + px], iv, bias[k]);
        m = fmaxf(m, l[j]);
    }
    MX[kh][px] = m;
    __syncthreads();
    m = fmaxf(MX[0][px], MX[1][px]);
    float s = 0.f;
#pragma unroll
    for (int j = 0; j < 32; ++j) {
        l[j] = __expf(l[j] - m);
        s += l[j];
    }
    SM[kh][px] = s;
    __syncthreads();
    s = SM[0][px] + SM[1][px];
    float si = 1.0f / s;
#pragma unroll
    for (int j = 0; j < 32; ++j) {
        int k = (kh << 5) + j;
        float v = l[j] * si;
        float vh = __shfl_xor(v, 1);
        if (!(px & 1))
            sab[(((size_t)(n * KK + k) << 10) + p0 + px) >> 1] = bfpair(v, vh);
    }
}

// ---------------- vpart[half][n][k][c] = sum_{p in half} sa*xnorm  (MFMA) ----------------
// grid: 512 blocks = n(32) x p-half(2) x 64-c tile(8). 512 threads = 8 waves. (R9 verbatim)
__global__ void __launch_bounds__(512, 2) k_vlad(
        const float* __restrict__ x, const unsigned int* __restrict__ sab,
        const float* __restrict__ inv_n, float* __restrict__ vpart,
        float* __restrict__ Spart) {
    int b = blockIdx.x;
    int nb = b >> 4;
    int half = (b >> 3) & 1;
    int c0 = (b & 7) << 6;
    int tid = threadIdx.x;
    int lane = tid & 63;
    int wv = __builtin_amdgcn_readfirstlane(tid >> 6);   // 0..7
    int l15 = lane & 15, l4 = lane >> 4;
    int kt = wv & 3;
    int ctb = (wv >> 2) << 1;      // 0 or 2

    __shared__ unsigned int smem_u[8448];   // 33792 B
    unsigned int* SAB = smem_u;             // [2][64][33] sa bf16 pairs
    unsigned int* XT  = smem_u + 4224;      // [2][64][33] xn bf16 pairs

    int tr = tid >> 3;             // row 0..63 (k for sa, c for x)
    int tc = tid & 7;              // col group 0..7

    const unsigned int* sap = sab + ((size_t)(nb * KK + tr) << 9) + (half << 8) + (tc << 2);
    const float* xbp = x + (size_t)(nb * CC + c0 + tr) * PP + (half << 9) + (tc << 3);
    const float* ivp = inv_n + nb * PP + (half << 9) + (tc << 3);

    f32x4 acc0 = {0.f, 0.f, 0.f, 0.f};
    f32x4 acc1 = {0.f, 0.f, 0.f, 0.f};
    float sacc = 0.f;

    u32x4 sregA, sregB;
    float4 xrA0, xrA1, xrB0, xrB1, ivA0, ivA1, ivB0, ivB1;

#define LOADA(i) { sregA = *(const u32x4*)(sap + (i) * 32); \
        xrA0 = *(const float4*)(xbp + (i) * 64); \
        xrA1 = *(const float4*)(xbp + (i) * 64 + 4); \
        ivA0 = *(const float4*)(ivp + (i) * 64); \
        ivA1 = *(const float4*)(ivp + (i) * 64 + 4); }
#define LOADB(i) { sregB = *(const u32x4*)(sap + (i) * 32); \
        xrB0 = *(const float4*)(xbp + (i) * 64); \
        xrB1 = *(const float4*)(xbp + (i) * 64 + 4); \
        ivB0 = *(const float4*)(ivp + (i) * 64); \
        ivB1 = *(const float4*)(ivp + (i) * 64 + 4); }

#define BODY(SREG, XR0, XR1, IV0, IV1, i, LOADNEXT) { \
        __syncthreads(); \
        int bo = ((i) & 1) * 2112; \
        *(u32x4*)(SAB + bo + tr * 33 + (tc << 2)) = SREG; \
        _Pragma("unroll") \
        for (int j = 0; j < 4; ++j) { \
            unsigned int uv = SREG[j]; \
            sacc += __builtin_bit_cast(float, uv << 16) \
                  + __builtin_bit_cast(float, uv & 0xFFFF0000u); \
        } \
        u32x4 xw; \
        xw[0] = bfpair(XR0.x * IV0.x, XR0.y * IV0.y); \
        xw[1] = bfpair(XR0.z * IV0.z, XR0.w * IV0.w); \
        xw[2] = bfpair(XR1.x * IV1.x, XR1.y * IV1.y); \
        xw[3] = bfpair(XR1.z * IV1.z, XR1.w * IV1.w); \
        *(u32x4*)(XT + bo + tr * 33 + (tc << 2)) = xw; \
        LOADNEXT; \
        __syncthreads(); \
        const unsigned int* sa_l = SAB + bo + (kt * 16 + l15) * 33 + (l4 << 2); \
        const unsigned int* xb0  = XT + bo + (ctb * 16 + l15) * 33 + (l4 << 2); \
        _Pragma("unroll") \
        for (int s = 0; s < 2; ++s) { \
            FragU af, bf0, bf1; \
            af.u  = *(const u32x4*)(sa_l + s * 16); \
            bf0.u = *(const u32x4*)(xb0 + s * 16); \
            bf1.u = *(const u32x4*)(xb0 + 16 * 33 + s * 16); \
            acc0 = __builtin_amdgcn_mfma_f32_16x16x32_bf16(af.h, bf0.h, acc0, 0, 0, 0); \
            acc1 = __builtin_amdgcn_mfma_f32_16x16x32_bf16(af.h, bf1.h, acc1, 0, 0, 0); \
        } \
    }

    LOADA(0); LOADB(1);
#pragma unroll 1
    for (int i = 0; i < 8; i += 2) {
        if (i < 6) { BODY(sregA, xrA0, xrA1, ivA0, ivA1, i, LOADA(i + 2)); }
        else       { BODY(sregA, xrA0, xrA1, ivA0, ivA1, i, ); }
        if (i < 5) { BODY(sregB, xrB0, xrB1, ivB0, ivB1, i + 1, LOADB(i + 3)); }
        else       { BODY(sregB, xrB0, xrB1, ivB0, ivB1, i + 1, ); }
    }
#undef LOADA
#undef LOADB
#undef BODY

    // ---- Spart[half][n][k]: reduce the 8 col-groups sharing row tr; c0-blocks write ----
    sacc += __shfl_xor(sacc, 1);
    sacc += __shfl_xor(sacc, 2);
    sacc += __shfl_xor(sacc, 4);
    if ((b & 7) == 0 && (lane & 7) == 0)
        Spart[(half * NN + nb) * KK + tr] = sacc;

    // ---- epilogue: write raw partial accumulators ----
    float* vbase = vpart + (size_t)half * NN * KK * CC;
#pragma unroll
    for (int r = 0; r < 4; ++r) {
        int k = kt * 16 + (l4 << 2) + r;
        int cg = c0 + ctb * 16 + l15;
        float* vp = vbase + ((size_t)nb * KK + k) * CC + cg;
        vp[0]  = acc0[r];
        vp[16] = acc1[r];
    }
}

// ---------------- vlad = vp0+vp1-S*cent; per-row sumsq + inv norm ----------------
__global__ void k_rownorm(const float* __restrict__ vp0, const float* __restrict__ vp1,
                          const float* __restrict__ Spart, const float* __restrict__ cent,
                          float* __restrict__ vlad, float* __restrict__ rinv,
                          float* __restrict__ rsq) {
    int r = blockIdx.x * 4 + (threadIdx.x >> 6);   // n*KK+k
    int lane = threadIdx.x & 63;
    int n = r >> 6, k = r & 63;
    float S = Spart[n * KK + k] + Spart[(NN + n) * KK + k];
    const float* a  = vp0 + (size_t)r * CC;
    const float* bq = vp1 + (size_t)r * CC;
    const float* cp = cent + (size_t)k * CC;
    float* vo = vlad + (size_t)r * CC;
    float s = 0.f;
#pragma unroll
    for (int i = 0; i < CC / 64; ++i) {
        int c = i * 64 + lane;
        float v = a[c] + bq[c] - S * cp[c];
        vo[c] = v;
        s = fmaf(v, v, s);
    }
#pragma unroll
    for (int off = 32; off > 0; off >>= 1) s += __shfl_xor(s, off);
    if (lane == 0) {
        float iv = 1.0f / fmaxf(sqrtf(s), EPS);
        rinv[r] = iv;
        rsq[r] = s * iv * iv;
    }
}

// ---------------- final scale (tinv computed in-block from rsq) ----------------
__global__ void k_final(const float* __restrict__ vlad, const float* __restrict__ rinv,
                        const float* __restrict__ rsq, float* __restrict__ out) {
    size_t i4 = (size_t)blockIdx.x * 256 + threadIdx.x;   // over 262144 float4s
    int row = (int)(i4 >> 7);
    int n = row >> 6;
    int lane = threadIdx.x & 63;
    float s = rsq[(n << 6) + lane];
#pragma unroll
    for (int off = 32; off > 0; off >>= 1) s += __shfl_xor(s, off);
    float tinv = 1.0f / fmaxf(sqrtf(s), EPS);
    float4 v = ((const float4*)vlad)[i4];
    float sc = rinv[row] * tinv;
    float4 o{v.x * sc, v.y * sc, v.z * sc, v.w * sc};
    ((float4*)out)[i4] = o;
}

extern "C" void kernel_launch(void* const* d_in, const int* in_sizes, int n_in,
                              void* d_out, int out_size, void* d_ws, size_t ws_size,
                              hipStream_t stream) {
    const float* x    = (const float*)d_in[0];
    const float* w    = (const float*)d_in[1];
    const float* bias = (const float*)d_in[2];
    const float* cent = (const float*)d_in[3];
    float* ws = (float*)d_ws;

    float* vlad    = ws;                              // 1048576
    float* vpart   = vlad + (size_t)NN * KK * CC;     // 2097152 (two halves)
    float* Spart   = vpart + (size_t)2 * NN * KK * CC;// 4096
    float* rinv    = Spart + 2 * NN * KK;             // 2048
    float* rsq     = rinv + NN * KK;                  // 2048
    float* inv_n   = rsq + NN * KK;                   // 32768
    float* ssqpart = inv_n + NN * PP;                 // 65536 (two halves)
    float* lgpart  = ssqpart + 2 * NN * PP;           // 4194304 (two halves)
    unsigned int* wpk = (unsigned int*)(lgpart + (size_t)2 * NN * KK * PP);  // 16384
    unsigned int* sab = wpk + KK * CC / 2;            // 1048576 u32

    float* out = (float*)d_out;

    k_wprep<<<dim3(64), dim3(256), 0, stream>>>(w, wpk);
    k_lgemm<<<dim3(512), dim3(512), 0, stream>>>(x, wpk, lgpart, ssqpart);
    k_combine<<<dim3(256), dim3(256), 0, stream>>>(lgpart, ssqpart, bias, inv_n, sab);
    k_vlad<<<dim3(512), dim3(512), 0, stream>>>(x, sab, inv_n, vpart, Spart);
    k_rownorm<<<dim3(NN * KK / 4), dim3(256), 0, stream>>>(
        vpart, vpart + (size_t)NN * KK * CC, Spart, cent, vlad, rinv, rsq);
    k_final<<<dim3(1024), dim3(256), 0, stream>>>(vlad, rinv, rsq, out);
}

// Round 13
// 63.879 us; speedup vs baseline: 1.2745x; 1.2745x over previous
//
#include <hip/hip_runtime.h>
#include <math.h>

#define NN 32
#define CC 512
#define PP 1024   // H*W
#define KK 64
static constexpr float EPS = 1e-12f;

typedef __attribute__((ext_vector_type(8))) short bf16x8;
typedef __attribute__((ext_vector_type(4))) float f32x4;
typedef __attribute__((ext_vector_type(4))) unsigned int u32x4;
union FragU { u32x4 u; bf16x8 h; };

// pack two fp32 into one u32 of 2 bf16 (RNE)
__device__ __forceinline__ unsigned int bfpair(float lo, float hi) {
    unsigned int ul = __builtin_bit_cast(unsigned int, lo);
    unsigned int uh = __builtin_bit_cast(unsigned int, hi);
    ul = ul + 0x7FFFu + ((ul >> 16) & 1u);
    uh = uh + 0x7FFFu + ((uh >> 16) & 1u);
    return (ul >> 16) | (uh & 0xFFFF0000u);
}

// ---------------- fused pixnorm + logits(MFMA) + softmax -> sab=(sa*iv) bf16, Spart ----------------
// grid: 256 blocks = n(32) x 128-px tile(8). 512 threads = 8 waves.
// Monolithic W in LDS (converted from fp32 in-kernel; k_wprep folded in).
__global__ void __launch_bounds__(512, 2) k_logits(
        const float* __restrict__ x, const float* __restrict__ w,
        const float* __restrict__ bias, unsigned int* __restrict__ sab,
        float* __restrict__ Spart) {
    int b = blockIdx.x;
    int n = b >> 3;
    int p0 = (b & 7) << 7;           // 128-px tile base
    int tid = threadIdx.x;
    int lane = tid & 63;
    int wv = __builtin_amdgcn_readfirstlane(tid >> 6);   // 0..7 = px tile
    int l15 = lane & 15, l4 = lane >> 4;
    int rp = tid >> 4;               // staging cpair row 0..31
    int px8 = (tid & 15) << 3;       // staging px octet

    __shared__ unsigned int smem_u[26240];   // 104960 B
    unsigned int* XP  = smem_u;              // 2 x [128][33] u32
    unsigned int* WBF = smem_u + 8448;       // [64][260] u32
    float* RED  = (float*)(smem_u + 25088);  // [8][128] ssq / S partials
    float* REDI = (float*)(smem_u + 26112);  // [128] inv per px

    // ---- stage whole W (fp32 -> bf16 pairs) into LDS once ----
    {
        int k = tid >> 3, cb = (tid & 7) << 5;   // cb in u32 pairs (32 pairs = 64 floats)
        const float* wsrc = w + (k << 9) + (cb << 1);
#pragma unroll
        for (int i = 0; i < 8; ++i) {
            float4 f0 = *(const float4*)&wsrc[(i << 3)];
            float4 f1 = *(const float4*)&wsrc[(i << 3) + 4];
            u32x4 v;
            v[0] = bfpair(f0.x, f0.y); v[1] = bfpair(f0.z, f0.w);
            v[2] = bfpair(f1.x, f1.y); v[3] = bfpair(f1.z, f1.w);
            *(u32x4*)&WBF[k * 260 + cb + (i << 2)] = v;
        }
    }

    const float* xb = x + (size_t)n * CC * PP + p0;

    f32x4 c0v = {0.f, 0.f, 0.f, 0.f};
    f32x4 c1v = {0.f, 0.f, 0.f, 0.f};
    f32x4 c2v = {0.f, 0.f, 0.f, 0.f};
    f32x4 c3v = {0.f, 0.f, 0.f, 0.f};
    float ssq[8] = {};
    float4 a0, a1, b0, b1;

#define PFL(i) { const float* xa = xb + (size_t)((i) * 64 + 2 * rp) * PP + px8; \
        a0 = *(const float4*)xa; a1 = *(const float4*)(xa + 4); \
        b0 = *(const float4*)(xa + PP); b1 = *(const float4*)(xa + PP + 4); }

#define MSTEP(H) { \
        FragU bfr; \
        int ob = xo + ((H) << 4); \
        bfr.u[0] = xq[ob]; bfr.u[1] = xq[ob + 1]; \
        bfr.u[2] = xq[ob + 2]; bfr.u[3] = xq[ob + 3]; \
        int oa = l15 * 260 + (i << 5) + ((H) << 4) + (l4 << 2); \
        FragU af; \
        af.u = *(const u32x4*)&WBF[oa]; \
        c0v = __builtin_amdgcn_mfma_f32_16x16x32_bf16(af.h, bfr.h, c0v, 0, 0, 0); \
        af.u = *(const u32x4*)&WBF[oa + 4160]; \
        c1v = __builtin_amdgcn_mfma_f32_16x16x32_bf16(af.h, bfr.h, c1v, 0, 0, 0); \
        af.u = *(const u32x4*)&WBF[oa + 8320]; \
        c2v = __builtin_amdgcn_mfma_f32_16x16x32_bf16(af.h, bfr.h, c2v, 0, 0, 0); \
        af.u = *(const u32x4*)&WBF[oa + 12480]; \
        c3v = __builtin_amdgcn_mfma_f32_16x16x32_bf16(af.h, bfr.h, c3v, 0, 0, 0); \
    }

    PFL(0);
#pragma unroll 1
    for (int i = 0; i < 8; ++i) {
        __syncthreads();   // buffer free + (i==0) WBF visible
        unsigned int* xp = XP + (i & 1) * 4224;
        float av[8] = {a0.x, a0.y, a0.z, a0.w, a1.x, a1.y, a1.z, a1.w};
        float bv[8] = {b0.x, b0.y, b0.z, b0.w, b1.x, b1.y, b1.z, b1.w};
#pragma unroll
        for (int j = 0; j < 8; ++j) {
            xp[(px8 + j) * 33 + rp] = bfpair(av[j], bv[j]);
            ssq[j] = fmaf(av[j], av[j], fmaf(bv[j], bv[j], ssq[j]));
        }
        if (i < 7) { PFL(i + 1); }
        __syncthreads();   // staged chunk visible
        const unsigned int* xq = XP + (i & 1) * 4224;
        int xo = (wv * 16 + l15) * 33 + (l4 << 2);
        MSTEP(0);
        MSTEP(1);
    }
#undef PFL
#undef MSTEP

    // ---- per-px ssq -> inv ----
#pragma unroll
    for (int j = 0; j < 8; ++j) {
        ssq[j] += __shfl_xor(ssq[j], 16);
        ssq[j] += __shfl_xor(ssq[j], 32);
    }
    if (l4 == 0) {
#pragma unroll
        for (int j = 0; j < 8; ++j) RED[(wv << 7) + px8 + j] = ssq[j];
    }
    __syncthreads();
    if (tid < 128) {
        float s = 0.f;
#pragma unroll
        for (int w8 = 0; w8 < 8; ++w8) s += RED[(w8 << 7) + tid];
        REDI[tid] = 1.0f / fmaxf(sqrtf(s), EPS);
    }
    __syncthreads();

    // ---- softmax over 64 k (in-lane 16 + shfl over l4) ----
    float inv = REDI[(wv << 4) + l15];
    float lg[16];
#pragma unroll
    for (int r = 0; r < 4; ++r) {
        lg[r]      = c0v[r];
        lg[4 + r]  = c1v[r];
        lg[8 + r]  = c2v[r];
        lg[12 + r] = c3v[r];
    }
    float m = -1e30f;
#pragma unroll
    for (int kk = 0; kk < 16; ++kk) {
        int k = ((kk >> 2) << 4) + (l4 << 2) + (kk & 3);
        lg[kk] = fmaf(lg[kk], inv, bias[k]);
        m = fmaxf(m, lg[kk]);
    }
    m = fmaxf(m, __shfl_xor(m, 16));
    m = fmaxf(m, __shfl_xor(m, 32));
    float sm = 0.f;
#pragma unroll
    for (int kk = 0; kk < 16; ++kk) {
        lg[kk] = __expf(lg[kk] - m);
        sm += lg[kk];
    }
    sm += __shfl_xor(sm, 16);
    sm += __shfl_xor(sm, 32);
    float si = 1.0f / sm;

    // ---- store sab = sa*iv (bf16 pairs) + S partials ----
    int pcol = p0 + (wv << 4) + l15;
#pragma unroll
    for (int kk = 0; kk < 16; ++kk) {
        int k = ((kk >> 2) << 4) + (l4 << 2) + (kk & 3);
        float v = lg[kk] * si;                 // sa
        float vs = v;
        vs += __shfl_xor(vs, 1);
        vs += __shfl_xor(vs, 2);
        vs += __shfl_xor(vs, 4);
        vs += __shfl_xor(vs, 8);               // sum over the wave's 16 px
        float vi = v * inv;                    // sa*iv
        float vh = __shfl_xor(vi, 1);
        if ((l15 & 1) == 0)
            sab[(((size_t)(n * KK + k) << 10) + pcol) >> 1] = bfpair(vi, vh);
        if (l15 == 0) RED[(wv << 6) + k] = vs;
    }
    __syncthreads();
    if (tid < 64) {
        float s = 0.f;
#pragma unroll
        for (int w8 = 0; w8 < 8; ++w8) s += RED[(w8 << 6) + tid];
        Spart[(((b & 7) * NN) + n) * KK + tid] = s;
    }
}

// ---------------- vpart[half][n][k][c] = sum_{p in half} (sa*iv)*x  (MFMA) ----------------
// grid: 512 blocks = n(32) x p-half(2) x 64-c tile(8). 512 threads = 8 waves.
// Pure copy-and-MFMA staging: sab u32x4 + x fp32 -> 4 bfpair (no iv, no S decode).
__global__ void __launch_bounds__(512, 2) k_vlad(
        const float* __restrict__ x, const unsigned int* __restrict__ sab,
        float* __restrict__ vpart) {
    int b = blockIdx.x;
    int nb = b >> 4;
    int half = (b >> 3) & 1;
    int c0 = (b & 7) << 6;
    int tid = threadIdx.x;
    int lane = tid & 63;
    int wv = __builtin_amdgcn_readfirstlane(tid >> 6);   // 0..7
    int l15 = lane & 15, l4 = lane >> 4;
    int kt = wv & 3;
    int ctb = (wv >> 2) << 1;      // 0 or 2

    __shared__ unsigned int smem_u[8448];   // 33792 B
    unsigned int* SAB = smem_u;             // [2][64][33] sa*iv bf16 pairs
    unsigned int* XT  = smem_u + 4224;      // [2][64][33] x bf16 pairs

    int tr = tid >> 3;             // row 0..63 (k for sa, c for x)
    int tc = tid & 7;              // col group 0..7

    const unsigned int* sap = sab + ((size_t)(nb * KK + tr) << 9) + (half << 8) + (tc << 2);
    const float* xbp = x + (size_t)(nb * CC + c0 + tr) * PP + (half << 9) + (tc << 3);

    f32x4 acc0 = {0.f, 0.f, 0.f, 0.f};
    f32x4 acc1 = {0.f, 0.f, 0.f, 0.f};

    u32x4 sregA, sregB;
    float4 xrA0, xrA1, xrB0, xrB1;

#define LOADA(i) { sregA = *(const u32x4*)(sap + (i) * 32); \
        xrA0 = *(const float4*)(xbp + (i) * 64); \
        xrA1 = *(const float4*)(xbp + (i) * 64 + 4); }
#define LOADB(i) { sregB = *(const u32x4*)(sap + (i) * 32); \
        xrB0 = *(const float4*)(xbp + (i) * 64); \
        xrB1 = *(const float4*)(xbp + (i) * 64 + 4); }

#define BODY(SREG, XR0, XR1, i, LOADNEXT) { \
        __syncthreads(); \
        int bo = ((i) & 1) * 2112; \
        *(u32x4*)(SAB + bo + tr * 33 + (tc << 2)) = SREG; \
        u32x4 xw; \
        xw[0] = bfpair(XR0.x, XR0.y); \
        xw[1] = bfpair(XR0.z, XR0.w); \
        xw[2] = bfpair(XR1.x, XR1.y); \
        xw[3] = bfpair(XR1.z, XR1.w); \
        *(u32x4*)(XT + bo + tr * 33 + (tc << 2)) = xw; \
        LOADNEXT; \
        __syncthreads(); \
        const unsigned int* sa_l = SAB + bo + (kt * 16 + l15) * 33 + (l4 << 2); \
        const unsigned int* xb0  = XT + bo + (ctb * 16 + l15) * 33 + (l4 << 2); \
        _Pragma("unroll") \
        for (int s = 0; s < 2; ++s) { \
            FragU af, bf0, bf1; \
            af.u  = *(const u32x4*)(sa_l + s * 16); \
            bf0.u = *(const u32x4*)(xb0 + s * 16); \
            bf1.u = *(const u32x4*)(xb0 + 16 * 33 + s * 16); \
            acc0 = __builtin_amdgcn_mfma_f32_16x16x32_bf16(af.h, bf0.h, acc0, 0, 0, 0); \
            acc1 = __builtin_amdgcn_mfma_f32_16x16x32_bf16(af.h, bf1.h, acc1, 0, 0, 0); \
        } \
    }

    LOADA(0); LOADB(1);
#pragma unroll 1
    for (int i = 0; i < 8; i += 2) {
        if (i < 6) { BODY(sregA, xrA0, xrA1, i, LOADA(i + 2)); }
        else       { BODY(sregA, xrA0, xrA1, i, ); }
        if (i < 5) { BODY(sregB, xrB0, xrB1, i + 1, LOADB(i + 3)); }
        else       { BODY(sregB, xrB0, xrB1, i + 1, ); }
    }
#undef LOADA
#undef LOADB
#undef BODY

    // ---- epilogue: write raw partial accumulators ----
    float* vbase = vpart + (size_t)half * NN * KK * CC;
#pragma unroll
    for (int r = 0; r < 4; ++r) {
        int k = kt * 16 + (l4 << 2) + r;
        int cg = c0 + ctb * 16 + l15;
        float* vp = vbase + ((size_t)nb * KK + k) * CC + cg;
        vp[0]  = acc0[r];
        vp[16] = acc1[r];
    }
}

// ---------------- vlad = vp0+vp1-S*cent; per-row sumsq + inv norm ----------------
__global__ void k_rownorm(const float* __restrict__ vp0, const float* __restrict__ vp1,
                          const float* __restrict__ Spart, const float* __restrict__ cent,
                          float* __restrict__ vlad, float* __restrict__ rinv,
                          float* __restrict__ rsq) {
    int r = blockIdx.x * 4 + (threadIdx.x >> 6);   // n*KK+k
    int lane = threadIdx.x & 63;
    int n = r >> 6, k = r & 63;
    float S = 0.f;
#pragma unroll
    for (int pt = 0; pt < 8; ++pt) S += Spart[(pt * NN + n) * KK + k];
    const float* a  = vp0 + (size_t)r * CC;
    const float* bq = vp1 + (size_t)r * CC;
    const float* cp = cent + (size_t)k * CC;
    float* vo = vlad + (size_t)r * CC;
    float s = 0.f;
#pragma unroll
    for (int i = 0; i < CC / 64; ++i) {
        int c = i * 64 + lane;
        float v = a[c] + bq[c] - S * cp[c];
        vo[c] = v;
        s = fmaf(v, v, s);
    }
#pragma unroll
    for (int off = 32; off > 0; off >>= 1) s += __shfl_xor(s, off);
    if (lane == 0) {
        float iv = 1.0f / fmaxf(sqrtf(s), EPS);
        rinv[r] = iv;
        rsq[r] = s * iv * iv;
    }
}

// ---------------- final scale (tinv computed in-block from rsq) ----------------
__global__ void k_final(const float* __restrict__ vlad, const float* __restrict__ rinv,
                        const float* __restrict__ rsq, float* __restrict__ out) {
    size_t i4 = (size_t)blockIdx.x * 256 + threadIdx.x;   // over 262144 float4s
    int row = (int)(i4 >> 7);
    int n = row >> 6;
    int lane = threadIdx.x & 63;
    float s = rsq[(n << 6) + lane];
#pragma unroll
    for (int off = 32; off > 0; off >>= 1) s += __shfl_xor(s, off);
    float tinv = 1.0f / fmaxf(sqrtf(s), EPS);
    float4 v = ((const float4*)vlad)[i4];
    float sc = rinv[row] * tinv;
    float4 o{v.x * sc, v.y * sc, v.z * sc, v.w * sc};
    ((float4*)out)[i4] = o;
}

extern "C" void kernel_launch(void* const* d_in, const int* in_sizes, int n_in,
                              void* d_out, int out_size, void* d_ws, size_t ws_size,
                              hipStream_t stream) {
    const float* x    = (const float*)d_in[0];
    const float* w    = (const float*)d_in[1];
    const float* bias = (const float*)d_in[2];
    const float* cent = (const float*)d_in[3];
    float* ws = (float*)d_ws;

    float* vlad  = ws;                                // 1048576
    float* vpart = vlad + (size_t)NN * KK * CC;       // 2097152 (two halves)
    float* Spart = vpart + (size_t)2 * NN * KK * CC;  // 16384 (8 partials)
    float* rinv  = Spart + 8 * NN * KK;               // 2048
    float* rsq   = rinv + NN * KK;                    // 2048
    unsigned int* sab = (unsigned int*)(rsq + NN * KK);   // 1048576 u32 (sa*iv bf16 pairs)

    float* out = (float*)d_out;

    k_logits<<<dim3(256), dim3(512), 0, stream>>>(x, w, bias, sab, Spart);
    k_vlad<<<dim3(512), dim3(512), 0, stream>>>(x, sab, vpart);
    k_rownorm<<<dim3(NN * KK / 4), dim3(256), 0, stream>>>(
        vpart, vpart + (size_t)NN * KK * CC, Spart, cent, vlad, rinv, rsq);
    k_final<<<dim3(1024), dim3(256), 0, stream>>>(vlad, rinv, rsq, out);
}